// Round 10
// baseline (210.943 us; speedup 1.0000x reference)
//
#include <hip/hip_runtime.h>

// B=8, C=64, D=8 (q/k), H=W=128.  dwconv3x3 -> CCA -> CCA -> pointwise.
// Round 15.  r10-r14 plateau (203-207us) across very different ccdir
// internals => ccdir internals not critical path.  Grid arithmetic: ccdir
// grid (2048) == resident cohort (8/CU x 256) -> all blocks stage/compute/
// write in lockstep, no inter-block pipelining; pw (1024) likewise.  Fix:
// multi-item blocks with cross-item register prefetch (T14 async-STAGE):
//   ccdir grid (32,8,2), 4 items/block: after writing item i's staged regs
//   to LDS, issue item i+1's 4x global_load_dwordx4 -> in flight across
//   the whole item-i compute.  pw grid (64,8), 2 items/block, same.
// Rest identical to r14 (LDS time-share 20480B, no launch-bounds clamps).
// Fragment layouts (mfma_f32_16x16x32_bf16):
//   A[m=lane&15][k=quad*8+j (+32s)], B[k][n=lane&15], C col=lane&15,row=quad*4+reg
// (mfma_f32_16x16x16bf16_1k): A[m=lane&15][k=quad*4+j], B[k=quad*4+j][n=lane&15],
//   C col=lane&15,row=quad*4+reg.

#define NEGINF -3.0e38f

typedef __attribute__((ext_vector_type(8))) __bf16 bf8;
typedef __attribute__((ext_vector_type(4))) __bf16 bf4;
typedef __attribute__((ext_vector_type(4))) short s4;
typedef __attribute__((ext_vector_type(4))) float f4;

__device__ __forceinline__ f4 MFMA(bf8 a, bf8 b, f4 c) {
  return __builtin_amdgcn_mfma_f32_16x16x32_bf16(a, b, c, 0, 0, 0);
}
__device__ __forceinline__ f4 MFMA16(bf4 a, bf4 b, f4 c) {
  return __builtin_amdgcn_mfma_f32_16x16x16bf16_1k(*(s4*)&a, *(s4*)&b, c, 0, 0, 0);
}
__device__ __forceinline__ ushort bfb(float f) {
  __bf16 h = (__bf16)f;
  return *(ushort*)&h;
}

// 32x32-tile dwconv3x3; writes y and yT (bf16), packed ushort2 stores.
// Block (0,0,0) lanes 0-63 also pack the weight-fragment tables (consumed
// by the NEXT launch; stream ordering guarantees visibility).
__global__ __launch_bounds__(256) void dwconv_kernel(
    const float* __restrict__ x, const float* __restrict__ wdw,
    __bf16* __restrict__ y, __bf16* __restrict__ yT,
    const float* __restrict__ wq, const float* __restrict__ wk,
    const float* __restrict__ wv, const float* __restrict__ wpw,
    __bf16* __restrict__ wtab, __bf16* __restrict__ ptab) {
  __shared__ float in[34][36];
  __shared__ float ot[32][33];
  if (blockIdx.x == 0 && blockIdx.y == 0 && blockIdx.z == 0 &&
      threadIdx.x < 64) {
    int lane = threadIdx.x;
    int l16 = lane & 15, quad = lane >> 4;
    const float* wr = (l16 < 8) ? (wq + l16*64) : (wk + (l16 - 8)*64);
    float scale = (l16 < 8) ? 1.4426950408889634f : 1.0f;   // log2(e) on wq
    for (int s = 0; s < 2; ++s)
      for (int j = 0; j < 8; ++j)
        wtab[(s*64 + lane)*8 + j] = (__bf16)(wr[quad*8 + s*32 + j]*scale);
    for (int m0 = 0; m0 < 4; ++m0) {
      const float* vr = wv + (m0*16 + l16)*64;
      const float* pr = wpw + (m0*16 + l16)*64;
      for (int s = 0; s < 2; ++s)
        for (int j = 0; j < 8; ++j) {
          wtab[((2 + m0*2 + s)*64 + lane)*8 + j] = (__bf16)vr[quad*8 + s*32 + j];
          ptab[((m0*2 + s)*64 + lane)*8 + j]     = (__bf16)pr[quad*8 + s*32 + j];
        }
    }
  }
  int tx = threadIdx.x & 31, ty = threadIdx.x >> 5;   // 32x8
  int w0 = blockIdx.x*32, h0 = blockIdx.y*32;
  int n = blockIdx.z;                                  // b*64 + c
  const float* xp = x + (size_t)n*16384;
  const float* wp = wdw + (n & 63)*9;
  float wr[9];
  #pragma unroll
  for (int j = 0; j < 9; ++j) wr[j] = wp[j];
  for (int idx = threadIdx.x; idx < 1156; idx += 256) {  // 34*34 linear
    int i = idx/34, j = idx - i*34;
    int hh = h0 + i - 1, ww = w0 + j - 1;
    float v = 0.f;
    if (hh >= 0 && hh < 128 && ww >= 0 && ww < 128) v = xp[hh*128 + ww];
    in[i][j] = v;
  }
  __syncthreads();
  for (int i2 = ty; i2 < 32; i2 += 8) {
    float acc = 0.f;
    #pragma unroll
    for (int kh = 0; kh < 3; ++kh)
      #pragma unroll
      for (int kw = 0; kw < 3; ++kw)
        acc += wr[kh*3 + kw]*in[i2 + kh][tx + kw];
    ot[i2][tx] = acc;
  }
  __syncthreads();
  ushort* yp  = (ushort*)(y  + (size_t)n*16384);
  ushort* ytp = (ushort*)(yT + (size_t)n*16384);
  for (int idx = threadIdx.x; idx < 512; idx += 256) {
    int row = idx >> 4, c2 = (idx & 15)*2;
    ushort2 u;
    u.x = bfb(ot[row][c2]); u.y = bfb(ot[row][c2 + 1]);
    *(ushort2*)&yp[(size_t)(h0 + row)*128 + w0 + c2] = u;
    ushort2 v;
    v.x = bfb(ot[c2][row]); v.y = bfb(ot[c2 + 1][row]);
    *(ushort2*)&ytp[(size_t)(w0 + row)*128 + h0 + c2] = v;
  }
}

// Fused CCA direction kernel.  dir=0: src=A -> dstRow, stats sW.
// dir=1: src=dst=AT in place, diag mask, stats sH.
// Output UNNORMALIZED: O[d][p] = sum_c exp2(e(p,c)) * v[d][c].
// 4 items/block (r = bx + 32*it) with cross-item register prefetch.
// LDS time-share: region A @0 (18432) = ys (staging) -> vs[64][140]
// (after B0b) -> per-wave out-stage [64][36] (after B2); ks @18432 (2048).
__global__ __launch_bounds__(256) void ccdir_kernel(
    const __bf16* __restrict__ srcRow, __bf16* __restrict__ dstRow,
    __bf16* __restrict__ srcdstCol,
    const __bf16* __restrict__ wtab,
    float* __restrict__ sW, float* __restrict__ sH) {
  __shared__ __align__(16) char smem[20480];
  __bf16* ys = (__bf16*)smem;
  __bf16* vs = (__bf16*)smem;                 // alias (post-B0b)
  __bf16* ks = (__bf16*)(smem + 18432);

  int t = threadIdx.x;
  int b = blockIdx.y, dir = blockIdx.z;
  const __bf16* src = dir ? srcdstCol : srcRow;
  __bf16* dst       = dir ? srcdstCol : dstRow;
  float* so         = dir ? sH : sW;
  const size_t base = (size_t)b*1048576;

  int lane = t & 63, w = t >> 6;
  int l16 = lane & 15, quad = lane >> 4;
  int a = t & 15, cp = t >> 4;              // staging indices

  f4 z4 = {0.f, 0.f, 0.f, 0.f};
  bf4 zb4;
  #pragma unroll
  for (int j = 0; j < 4; ++j) zb4[j] = (__bf16)0.f;

  // issue item-0 staging loads
  uint4 U[2][2];
  {
    const ushort* sp = (const ushort*)(src + base + (size_t)blockIdx.x*128);
    #pragma unroll
    for (int q = 0; q < 2; ++q) {
      int c = 2*cp + 32*q;
      U[q][0] = *(const uint4*)&sp[(size_t)c*16384 + a*8];
      U[q][1] = *(const uint4*)&sp[(size_t)(c + 1)*16384 + a*8];
    }
  }

  for (int it = 0; it < 4; ++it) {
    int r = blockIdx.x + 32*it;

    // ---- write staged regs -> ys[p][c-swizzled] (consumes U) ----
    {
      ushort* yr = (ushort*)ys;
      #pragma unroll
      for (int q = 0; q < 2; ++q) {
        int c = 2*cp + 32*q;
        const ushort* p0 = (const ushort*)&U[q][0];
        const ushort* p1 = (const ushort*)&U[q][1];
        int cx = (((c >> 3) ^ a) & 7)*8 + (c & 7);   // swizzle by (p>>3)&7 == a&7
        #pragma unroll
        for (int j = 0; j < 8; ++j) {
          ushort2 uv; uv.x = p0[j]; uv.y = p1[j];
          *(ushort2*)&yr[(a*8 + j)*72 + cx] = uv;
        }
      }
    }
    // ---- prefetch item it+1 (in flight across this item's compute) ----
    if (it < 3) {
      const ushort* spn =
          (const ushort*)(src + base + (size_t)(blockIdx.x + 32*(it + 1))*128);
      #pragma unroll
      for (int q = 0; q < 2; ++q) {
        int c = 2*cp + 32*q;
        U[q][0] = *(const uint4*)&spn[(size_t)c*16384 + a*8];
        U[q][1] = *(const uint4*)&spn[(size_t)(c + 1)*16384 + a*8];
      }
    }
    bf8 a_qk[2];
    #pragma unroll
    for (int s = 0; s < 2; ++s)
      a_qk[s] = *(const bf8*)&wtab[(s*64 + lane)*8];
    __syncthreads();                      // B0: ys staged

    // ---- frag loads + QK proj (ys live) ----
    bf8 b_ys[2][2];
    #pragma unroll
    for (int nt = 0; nt < 2; ++nt) {
      int p = w*32 + nt*16 + l16;
      int hi = (p >> 3) & 7;
      #pragma unroll
      for (int s = 0; s < 2; ++s)
        b_ys[nt][s] = *(const bf8*)&ys[p*72 + ((s*4 + quad) ^ hi)*8];
    }
    // QK proj: rows 0-7 = Q (quads 0,1) stay in regs; rows 8-15 = K -> ks.
    bf4 bq[2];
    #pragma unroll
    for (int nt = 0; nt < 2; ++nt) {
      int p = w*32 + nt*16 + l16;
      f4 aqk = z4;
      aqk = MFMA(a_qk[0], b_ys[nt][0], aqk);
      aqk = MFMA(a_qk[1], b_ys[nt][1], aqk);
      bf4 cv;
      #pragma unroll
      for (int rg = 0; rg < 4; ++rg) cv[rg] = (__bf16)aqk[rg];
      if (quad >= 2)
        *(bf4*)&ks[p*8 + (quad & 1)*4] = cv;
      bq[nt] = (quad < 2) ? cv : zb4;
    }
    __syncthreads();                      // B0b: all b_ys in regs; ys dead

    // ---- V proj SWAPPED into vs (aliases ys region) ----
    #pragma unroll
    for (int m0 = 0; m0 < 4; ++m0) {
      bf8 aw0 = *(const bf8*)&wtab[((2 + m0*2 + 0)*64 + lane)*8];
      bf8 aw1 = *(const bf8*)&wtab[((2 + m0*2 + 1)*64 + lane)*8];
      #pragma unroll
      for (int nt = 0; nt < 2; ++nt) {
        f4 va = z4;
        va = MFMA(b_ys[nt][0], aw0, va);
        va = MFMA(b_ys[nt][1], aw1, va);
        bf4 vv;
        #pragma unroll
        for (int rg = 0; rg < 4; ++rg) vv[rg] = (__bf16)va[rg];
        *(bf4*)&vs[(m0*16 + l16)*140 + w*32 + nt*16 + quad*4] = vv;
      }
    }
    __syncthreads();                      // B1: ks/vs visible

    // ---- tail: E^T = MFMA16(K,Q) -> exp2 in-reg -> x16 PV (swapped) ----
    f4 acc[4][2];
    #pragma unroll
    for (int m0 = 0; m0 < 4; ++m0)
      #pragma unroll
      for (int nt = 0; nt < 2; ++nt) acc[m0][nt] = z4;
    float sm[2] = {0.f, 0.f};

    #pragma unroll
    for (int ct = 0; ct < 8; ++ct) {
      bf4 ak = (quad < 2) ? *(const bf4*)&ks[(ct*16 + l16)*8 + quad*4] : zb4;
      bf4 av[4];
      #pragma unroll
      for (int m0 = 0; m0 < 4; ++m0)
        av[m0] = *(const bf4*)&vs[(m0*16 + l16)*140 + ct*16 + quad*4];
      #pragma unroll
      for (int nt = 0; nt < 2; ++nt) {
        f4 e = MFMA16(ak, bq[nt], z4);
        if (dir) {                        // diag mask: c == p
          int pg = w*32 + nt*16 + l16, c0 = ct*16 + quad*4;
          #pragma unroll
          for (int rg = 0; rg < 4; ++rg)
            if (c0 + rg == pg) e[rg] = NEGINF;
        }
        bf4 pb;
        #pragma unroll
        for (int rg = 0; rg < 4; ++rg) {
          float pv = exp2f(e[rg]);        // wq pre-scaled by log2(e)
          sm[nt] += pv;
          pb[rg] = (__bf16)pv;
        }
        #pragma unroll
        for (int m0 = 0; m0 < 4; ++m0)
          acc[m0][nt] = MFMA16(pb, av[m0], acc[m0][nt]);
      }
    }

    // stats: reduce quads (lane holds partial S[p=l16])
    int sb = ((b*128 + r) << 7);
    #pragma unroll
    for (int nt = 0; nt < 2; ++nt) {
      float s2 = sm[nt];
      s2 += __shfl_xor(s2, 16, 64);
      s2 += __shfl_xor(s2, 32, 64);
      if (quad == 0) so[sb + w*32 + nt*16 + l16] = s2;
    }
    __syncthreads();                      // B2: vs dead; region A reusable

    // out-stage in own-wave slice of region A; coalesced uint4 writes
    __bf16* oS = (__bf16*)(smem + 4608*w);   // [64][36] bf16
    #pragma unroll
    for (int m0 = 0; m0 < 4; ++m0)
      #pragma unroll
      for (int nt = 0; nt < 2; ++nt) {
        bf4 ov;
        #pragma unroll
        for (int rg = 0; rg < 4; ++rg) ov[rg] = (__bf16)acc[m0][nt][rg];
        *(bf4*)&oS[(m0*16 + l16)*36 + nt*16 + quad*4] = ov;
      }
    ushort* dp = (ushort*)(dst + base + (size_t)r*128 + w*32);
    ushort* oSu = (ushort*)oS;
    #pragma unroll
    for (int it2 = 0; it2 < 4; ++it2) {
      int i = it2*64 + lane;
      int d = i >> 2, ch = i & 3;
      uint2 lo  = *(const uint2*)&oSu[d*36 + ch*8];
      uint2 hi2 = *(const uint2*)&oSu[d*36 + ch*8 + 4];
      uint4 uu; uu.x = lo.x; uu.y = lo.y; uu.z = hi2.x; uu.w = hi2.y;
      *(uint4*)&dp[(size_t)d*16384 + ch*8] = uu;
    }
    __syncthreads();                      // B3: region A free for next item
  }
}

// Fused scale+combine:  Bo = gamma*(Bo + oT^T)/(sW+sH) + A.  Optionally
// writes Bo^T into BoT (may alias oT; tile staged to LDS first).
// 16x16 threads, 2-wide x (ushort2/float2 traffic).
__global__ __launch_bounds__(256) void combineT_kernel(
    __bf16* __restrict__ Bo, const __bf16* oT,
    const __bf16* __restrict__ A,
    const float* __restrict__ sW, const float* __restrict__ sH,
    const float* __restrict__ gamma, __bf16* BoT, int writeT) {
  __shared__ float tile[32][33], ts[32][33];
  __shared__ float rt[32][33];
  int tx = threadIdx.x, ty = threadIdx.y;       // 16x16
  int n = blockIdx.z;                           // b*64 + d
  int b = n >> 6;
  int x0 = blockIdx.x*32, y0 = blockIdx.y*32;
  const ushort* ip = (const ushort*)(oT + (size_t)n*16384);
  const float* shp = sH + b*16384;
  for (int i = ty; i < 32; i += 16) {
    ushort2 u = *(const ushort2*)&ip[(size_t)(y0 + i)*128 + x0 + 2*tx];
    tile[i][2*tx]     = (float)*(__bf16*)&u.x;
    tile[i][2*tx + 1] = (float)*(__bf16*)&u.y;
    float2 s2 = *(const float2*)&shp[(y0 + i)*128 + x0 + 2*tx];
    ts[i][2*tx] = s2.x; ts[i][2*tx + 1] = s2.y;
  }
  __syncthreads();
  float g = *gamma;
  for (int i2 = ty; i2 < 32; i2 += 16) {
    int h = x0 + i2, w2 = y0 + 2*tx;
    size_t idx = (size_t)n*16384 + (size_t)h*128 + w2;
    int pix = b*16384 + h*128 + w2;
    float2 swv = *(const float2*)&sW[pix];
    ushort2 bo = *(const ushort2*)((const ushort*)Bo + idx);
    ushort2 aa = *(const ushort2*)((const ushort*)A + idx);
    float inv0 = 1.0f/(swv.x + ts[2*tx][i2]);
    float r0 = g*((float)*(__bf16*)&bo.x + tile[2*tx][i2])*inv0
               + (float)*(__bf16*)&aa.x;
    float inv1 = 1.0f/(swv.y + ts[2*tx + 1][i2]);
    float r1 = g*((float)*(__bf16*)&bo.y + tile[2*tx + 1][i2])*inv1
               + (float)*(__bf16*)&aa.y;
    ushort2 o; o.x = bfb(r0); o.y = bfb(r1);
    *(ushort2*)((ushort*)Bo + idx) = o;
    rt[i2][2*tx] = r0; rt[i2][2*tx + 1] = r1;
  }
  if (writeT) {
    __syncthreads();
    for (int i = ty; i < 32; i += 16) {
      ushort2 o;
      o.x = bfb(rt[2*tx][i]); o.y = bfb(rt[2*tx + 1][i]);
      *(ushort2*)((ushort*)BoT + (size_t)n*16384 +
                  (size_t)(y0 + i)*128 + x0 + 2*tx) = o;
    }
  }
}

// MFMA pointwise 64->64 per (b,r) slice: out[o][p] = sum_c wpw[o][c]*A[c][p].
// 2 items/block (r = bx + 64*it) with cross-item register prefetch.
// Staged coalesced loads; SWAPPED MFMA -> p-major f32 acc stored direct
// (64B full-sector segments).  LDS 18432.
__global__ __launch_bounds__(256) void pw_kernel(
    const __bf16* __restrict__ A, const __bf16* __restrict__ ptab,
    float* __restrict__ out) {
  __shared__ __align__(16) char smem[18432];
  __bf16* ys = (__bf16*)smem;
  int t = threadIdx.x;
  int b = blockIdx.y;
  int lane = t & 63, w = t >> 6;
  int l16 = lane & 15, quad = lane >> 4;
  int a = t & 15, cp = t >> 4;
  const size_t base = (size_t)b*1048576;

  uint4 U[2][2];
  {
    const ushort* sp = (const ushort*)(A + base + (size_t)blockIdx.x*128);
    #pragma unroll
    for (int q = 0; q < 2; ++q) {
      int c = 2*cp + 32*q;
      U[q][0] = *(const uint4*)&sp[(size_t)c*16384 + a*8];
      U[q][1] = *(const uint4*)&sp[(size_t)(c + 1)*16384 + a*8];
    }
  }

  for (int it = 0; it < 2; ++it) {
    int r = blockIdx.x + 64*it;
    {
      ushort* yr = (ushort*)ys;
      #pragma unroll
      for (int q = 0; q < 2; ++q) {
        int c = 2*cp + 32*q;
        const ushort* p0 = (const ushort*)&U[q][0];
        const ushort* p1 = (const ushort*)&U[q][1];
        int cx = (((c >> 3) ^ a) & 7)*8 + (c & 7);
        #pragma unroll
        for (int j = 0; j < 8; ++j) {
          ushort2 uv; uv.x = p0[j]; uv.y = p1[j];
          *(ushort2*)&yr[(a*8 + j)*72 + cx] = uv;
        }
      }
    }
    if (it == 0) {                       // prefetch item 1
      const ushort* spn =
          (const ushort*)(A + base + (size_t)(blockIdx.x + 64)*128);
      #pragma unroll
      for (int q = 0; q < 2; ++q) {
        int c = 2*cp + 32*q;
        U[q][0] = *(const uint4*)&spn[(size_t)c*16384 + a*8];
        U[q][1] = *(const uint4*)&spn[(size_t)(c + 1)*16384 + a*8];
      }
    }
    __syncthreads();                     // ys staged
    bf8 b_ys[2][2];
    #pragma unroll
    for (int nt = 0; nt < 2; ++nt) {
      int p = w*32 + nt*16 + l16;
      int hi = (p >> 3) & 7;
      #pragma unroll
      for (int s = 0; s < 2; ++s)
        b_ys[nt][s] = *(const bf8*)&ys[p*72 + ((s*4 + quad) ^ hi)*8];
    }
    f4 z4 = {0.f, 0.f, 0.f, 0.f};
    float* dp = out + base + (size_t)r*128;
    #pragma unroll
    for (int m0 = 0; m0 < 4; ++m0) {
      bf8 aw0 = *(const bf8*)&ptab[((m0*2 + 0)*64 + lane)*8];
      bf8 aw1 = *(const bf8*)&ptab[((m0*2 + 1)*64 + lane)*8];
      #pragma unroll
      for (int nt = 0; nt < 2; ++nt) {
        f4 a2 = z4;
        a2 = MFMA(b_ys[nt][0], aw0, a2);
        a2 = MFMA(b_ys[nt][1], aw1, a2);
        *(f4*)&dp[(size_t)(m0*16 + l16)*16384 + w*32 + nt*16 + quad*4] = a2;
      }
    }
    __syncthreads();                     // all waves done reading ys
  }
}

extern "C" void kernel_launch(void* const* d_in, const int* in_sizes, int n_in,
                              void* d_out, int out_size, void* d_ws, size_t ws_size,
                              hipStream_t stream) {
  const float* x     = (const float*)d_in[0];
  const float* wdw   = (const float*)d_in[1];
  const float* wq    = (const float*)d_in[2];
  const float* wk    = (const float*)d_in[3];
  const float* wv    = (const float*)d_in[4];
  const float* gamma = (const float*)d_in[5];
  const float* wpw   = (const float*)d_in[6];
  float* out = (float*)d_out;

  // Workspace: y,z,AT bf16 (16 MB each) + wtab/ptab + 2 fp32 stat planes.
  __bf16* y    = (__bf16*)d_ws;
  __bf16* z    = y + 8388608;
  __bf16* AT   = z + 8388608;
  __bf16* wtab = AT + 8388608;        // 10 frags x 64 lanes x 8 = 5120
  __bf16* ptab = wtab + 5120;         // 8 frags x 64 lanes x 8 = 4096
  float* sW = (float*)(ptab + 4096);
  float* sH = sW + 131072;
  size_t need = (size_t)3*8388608*2 + (5120 + 4096)*2 + (size_t)2*131072*4;
  if (ws_size < need) return;

  dwconv_kernel<<<dim3(4, 4, 512), 256, 0, stream>>>(
      x, wdw, y, AT, wq, wk, wv, wpw, wtab, ptab);

  for (int pass = 0; pass < 2; ++pass) {
    const __bf16* A = pass ? z : y;   // CCA input / residual
    __bf16* Bo      = pass ? y : z;   // CCA output

    ccdir_kernel<<<dim3(32, 8, 2), 256, 0, stream>>>(
        A, Bo, AT, wtab, sW, sH);
    // pass 0: also write Bo^T into AT (next pass's transposed input)
    combineT_kernel<<<dim3(4, 4, 512), dim3(16, 16), 0, stream>>>(
        Bo, AT, A, sW, sH, gamma, AT, pass == 0 ? 1 : 0);
  }

  pw_kernel<<<dim3(64, 8), 256, 0, stream>>>(y, ptab, out);
}

// Round 11
// 206.183 us; speedup vs baseline: 1.0231x; 1.0231x over previous
//
#include <hip/hip_runtime.h>

// B=8, C=64, D=8 (q/k), H=W=128.  dwconv3x3 -> CCA -> CCA -> pointwise.
// Round 16.  r10-r15 plateau (203-211us) across every schedule-level ccdir
// variant => not schedule-bound.  Constant across all: global LAYOUT.
// Old [b*64+c][h][w] planes make ccdir/pw gather 64x256B @32KB stride per
// block (r12 visible ccdir: 2.4 TB/s vs fill 6.4).  This round: channel-
// interleaved layouts for intermediates (x/out fixed by harness):
//   R[b][h][c][w] for y,z,Bo  -> ccdir dir0 + pw read ONE contiguous 16KB
//     stream per block; dir0 writes contiguous 16KB plane (64B runs/wave).
//   T[b][w][c][h] for AT      -> dir1 reads/writes its plane contiguously.
// Kernel internals identical to r14 (MFMA frags, LDS swizzle+time-share,
// exp2, stats); only global address arithmetic changes.
// Fragment layouts (mfma_f32_16x16x32_bf16):
//   A[m=lane&15][k=quad*8+j (+32s)], B[k][n=lane&15], C col=lane&15,row=quad*4+reg
// (mfma_f32_16x16x16bf16_1k): A[m=lane&15][k=quad*4+j], B[k=quad*4+j][n=lane&15],
//   C col=lane&15,row=quad*4+reg.

#define NEGINF -3.0e38f

typedef __attribute__((ext_vector_type(8))) __bf16 bf8;
typedef __attribute__((ext_vector_type(4))) __bf16 bf4;
typedef __attribute__((ext_vector_type(4))) short s4;
typedef __attribute__((ext_vector_type(4))) float f4;

__device__ __forceinline__ f4 MFMA(bf8 a, bf8 b, f4 c) {
  return __builtin_amdgcn_mfma_f32_16x16x32_bf16(a, b, c, 0, 0, 0);
}
__device__ __forceinline__ f4 MFMA16(bf4 a, bf4 b, f4 c) {
  return __builtin_amdgcn_mfma_f32_16x16x16bf16_1k(*(s4*)&a, *(s4*)&b, c, 0, 0, 0);
}
__device__ __forceinline__ ushort bfb(float f) {
  __bf16 h = (__bf16)f;
  return *(ushort*)&h;
}

// 32x32-tile dwconv3x3; writes y (R-form) and yT (T-form), ushort2 stores.
// R(b,h,c,w) = ((b*128+h)*64+c)*128+w ; T(b,w,c,h) = ((b*128+w)*64+c)*128+h
// Block (0,0,0) lanes 0-63 also pack the weight-fragment tables (consumed
// by the NEXT launch; stream ordering guarantees visibility).
__global__ __launch_bounds__(256) void dwconv_kernel(
    const float* __restrict__ x, const float* __restrict__ wdw,
    __bf16* __restrict__ y, __bf16* __restrict__ yT,
    const float* __restrict__ wq, const float* __restrict__ wk,
    const float* __restrict__ wv, const float* __restrict__ wpw,
    __bf16* __restrict__ wtab, __bf16* __restrict__ ptab) {
  __shared__ float in[34][36];
  __shared__ float ot[32][33];
  if (blockIdx.x == 0 && blockIdx.y == 0 && blockIdx.z == 0 &&
      threadIdx.x < 64) {
    int lane = threadIdx.x;
    int l16 = lane & 15, quad = lane >> 4;
    const float* wr = (l16 < 8) ? (wq + l16*64) : (wk + (l16 - 8)*64);
    float scale = (l16 < 8) ? 1.4426950408889634f : 1.0f;   // log2(e) on wq
    for (int s = 0; s < 2; ++s)
      for (int j = 0; j < 8; ++j)
        wtab[(s*64 + lane)*8 + j] = (__bf16)(wr[quad*8 + s*32 + j]*scale);
    for (int m0 = 0; m0 < 4; ++m0) {
      const float* vr = wv + (m0*16 + l16)*64;
      const float* pr = wpw + (m0*16 + l16)*64;
      for (int s = 0; s < 2; ++s)
        for (int j = 0; j < 8; ++j) {
          wtab[((2 + m0*2 + s)*64 + lane)*8 + j] = (__bf16)vr[quad*8 + s*32 + j];
          ptab[((m0*2 + s)*64 + lane)*8 + j]     = (__bf16)pr[quad*8 + s*32 + j];
        }
    }
  }
  int tx = threadIdx.x & 31, ty = threadIdx.x >> 5;   // 32x8
  int w0 = blockIdx.x*32, h0 = blockIdx.y*32;
  int n = blockIdx.z;                                  // b*64 + c
  int b = n >> 6, c = n & 63;
  const float* xp = x + (size_t)n*16384;
  const float* wp = wdw + c*9;
  float wr[9];
  #pragma unroll
  for (int j = 0; j < 9; ++j) wr[j] = wp[j];
  for (int idx = threadIdx.x; idx < 1156; idx += 256) {  // 34*34 linear
    int i = idx/34, j = idx - i*34;
    int hh = h0 + i - 1, ww = w0 + j - 1;
    float v = 0.f;
    if (hh >= 0 && hh < 128 && ww >= 0 && ww < 128) v = xp[hh*128 + ww];
    in[i][j] = v;
  }
  __syncthreads();
  for (int i2 = ty; i2 < 32; i2 += 8) {
    float acc = 0.f;
    #pragma unroll
    for (int kh = 0; kh < 3; ++kh)
      #pragma unroll
      for (int kw = 0; kw < 3; ++kw)
        acc += wr[kh*3 + kw]*in[i2 + kh][tx + kw];
    ot[i2][tx] = acc;
  }
  __syncthreads();
  ushort* yp  = (ushort*)y;
  ushort* ytp = (ushort*)yT;
  for (int idx = threadIdx.x; idx < 512; idx += 256) {
    int row = idx >> 4, c2 = (idx & 15)*2;
    ushort2 u;
    u.x = bfb(ot[row][c2]); u.y = bfb(ot[row][c2 + 1]);
    *(ushort2*)&yp[(((size_t)b*128 + h0 + row)*64 + c)*128 + w0 + c2] = u;
    ushort2 v;
    v.x = bfb(ot[c2][row]); v.y = bfb(ot[c2 + 1][row]);
    *(ushort2*)&ytp[(((size_t)b*128 + w0 + row)*64 + c)*128 + h0 + c2] = v;
  }
}

// Fused CCA direction kernel.  dir=0: src=A (R) -> dstRow=Bo (R), stats sW.
// dir=1: src=dst=AT (T) in place, diag mask, stats sH.
// Output UNNORMALIZED: O[d][p] = sum_c exp2(e(p,c)) * v[d][c].
// Per-block plane = contiguous 16KB read AND write.
// LDS time-share: region A @0 (18432) = ys (staging) -> vs[64][140]
// (after B0b) -> per-wave out-stage [64][36] (after B2); ks @18432 (2048).
__global__ __launch_bounds__(256) void ccdir_kernel(
    const __bf16* __restrict__ srcRow, __bf16* __restrict__ dstRow,
    __bf16* __restrict__ srcdstCol,
    const __bf16* __restrict__ wtab,
    float* __restrict__ sW, float* __restrict__ sH) {
  __shared__ __align__(16) char smem[20480];
  __bf16* ys = (__bf16*)smem;
  __bf16* vs = (__bf16*)smem;                 // alias (post-B0b)
  __bf16* ks = (__bf16*)(smem + 18432);

  int t = threadIdx.x;
  int r = blockIdx.x, b = blockIdx.y, dir = blockIdx.z;
  const __bf16* src = dir ? srcdstCol : srcRow;
  __bf16* dst       = dir ? srcdstCol : dstRow;
  float* so         = dir ? sH : sW;
  const size_t plane = ((size_t)b*128 + r)*8192;   // [64][128] ush plane
  const ushort* sp = (const ushort*)src + plane;

  int lane = t & 63, w = t >> 6;
  int l16 = lane & 15, quad = lane >> 4;

  // ---- phase 0: stage Y[c][p] -> ys[p][c-swizzled] (contiguous source) ----
  {
    int a = t & 15, cp = t >> 4;          // p0 = a*8; channel pair 2cp(+32q)
    ushort* yr = (ushort*)ys;
    #pragma unroll
    for (int q = 0; q < 2; ++q) {
      int c = 2*cp + 32*q;
      uint4 u0 = *(const uint4*)&sp[(size_t)c*128 + a*8];
      uint4 u1 = *(const uint4*)&sp[(size_t)(c + 1)*128 + a*8];
      const ushort* p0 = (const ushort*)&u0;
      const ushort* p1 = (const ushort*)&u1;
      int cx = (((c >> 3) ^ a) & 7)*8 + (c & 7);   // swizzle by (p>>3)&7 == a&7
      #pragma unroll
      for (int j = 0; j < 8; ++j) {
        ushort2 uv; uv.x = p0[j]; uv.y = p1[j];
        *(ushort2*)&yr[(a*8 + j)*72 + cx] = uv;
      }
    }
  }
  bf8 a_qk[2];
  #pragma unroll
  for (int s = 0; s < 2; ++s)
    a_qk[s] = *(const bf8*)&wtab[(s*64 + lane)*8];
  __syncthreads();                      // B0: ys staged

  // ---- frag loads + QK proj (ys still live) ----
  f4 z4 = {0.f, 0.f, 0.f, 0.f};
  bf4 zb4;
  #pragma unroll
  for (int j = 0; j < 4; ++j) zb4[j] = (__bf16)0.f;
  bf8 b_ys[2][2];
  #pragma unroll
  for (int nt = 0; nt < 2; ++nt) {
    int p = w*32 + nt*16 + l16;
    int hi = (p >> 3) & 7;
    #pragma unroll
    for (int s = 0; s < 2; ++s)
      b_ys[nt][s] = *(const bf8*)&ys[p*72 + ((s*4 + quad) ^ hi)*8];
  }
  // QK proj: C rows 0-7 = Q (quads 0,1) stay in regs (== E-step B-frag);
  // rows 8-15 = K (quads 2,3) -> ks (separate region) via one b64.
  bf4 bq[2];
  #pragma unroll
  for (int nt = 0; nt < 2; ++nt) {
    int p = w*32 + nt*16 + l16;
    f4 aqk = z4;
    aqk = MFMA(a_qk[0], b_ys[nt][0], aqk);
    aqk = MFMA(a_qk[1], b_ys[nt][1], aqk);
    bf4 cv;
    #pragma unroll
    for (int rg = 0; rg < 4; ++rg) cv[rg] = (__bf16)aqk[rg];
    if (quad >= 2)
      *(bf4*)&ks[p*8 + (quad & 1)*4] = cv;
    bq[nt] = (quad < 2) ? cv : zb4;
  }
  __syncthreads();                      // B0b: all b_ys in regs; ys dead

  // ---- V proj SWAPPED into vs (aliases ys region) ----
  // lane holds V[d=m0*16+l16][p=w*32+nt*16+quad*4+rg] -> one b64 write.
  #pragma unroll
  for (int m0 = 0; m0 < 4; ++m0) {
    bf8 aw0 = *(const bf8*)&wtab[((2 + m0*2 + 0)*64 + lane)*8];
    bf8 aw1 = *(const bf8*)&wtab[((2 + m0*2 + 1)*64 + lane)*8];
    #pragma unroll
    for (int nt = 0; nt < 2; ++nt) {
      f4 va = z4;
      va = MFMA(b_ys[nt][0], aw0, va);
      va = MFMA(b_ys[nt][1], aw1, va);
      bf4 vv;
      #pragma unroll
      for (int rg = 0; rg < 4; ++rg) vv[rg] = (__bf16)va[rg];
      *(bf4*)&vs[(m0*16 + l16)*140 + w*32 + nt*16 + quad*4] = vv;
    }
  }
  __syncthreads();                      // B1: ks/vs visible

  // ---- tail: E^T = MFMA16(K,Q) -> exp2 in-reg -> x16 PV (swapped) ----
  f4 acc[4][2];
  #pragma unroll
  for (int m0 = 0; m0 < 4; ++m0)
    #pragma unroll
    for (int nt = 0; nt < 2; ++nt) acc[m0][nt] = z4;
  float sm[2] = {0.f, 0.f};

  #pragma unroll
  for (int ct = 0; ct < 8; ++ct) {
    bf4 ak = (quad < 2) ? *(const bf4*)&ks[(ct*16 + l16)*8 + quad*4] : zb4;
    bf4 av[4];
    #pragma unroll
    for (int m0 = 0; m0 < 4; ++m0)
      av[m0] = *(const bf4*)&vs[(m0*16 + l16)*140 + ct*16 + quad*4];
    #pragma unroll
    for (int nt = 0; nt < 2; ++nt) {
      f4 e = MFMA16(ak, bq[nt], z4);
      if (dir) {                        // diag mask: c == p
        int pg = w*32 + nt*16 + l16, c0 = ct*16 + quad*4;
        #pragma unroll
        for (int rg = 0; rg < 4; ++rg)
          if (c0 + rg == pg) e[rg] = NEGINF;
      }
      bf4 pb;
      #pragma unroll
      for (int rg = 0; rg < 4; ++rg) {
        float pv = exp2f(e[rg]);        // wq pre-scaled by log2(e)
        sm[nt] += pv;
        pb[rg] = (__bf16)pv;
      }
      #pragma unroll
      for (int m0 = 0; m0 < 4; ++m0)
        acc[m0][nt] = MFMA16(pb, av[m0], acc[m0][nt]);
    }
  }

  // stats: lane holds partial S[p=l16] over c = quad*4+rg (+16ct); reduce quads
  int sb = ((b*128 + r) << 7);
  #pragma unroll
  for (int nt = 0; nt < 2; ++nt) {
    float s2 = sm[nt];
    s2 += __shfl_xor(s2, 16, 64);
    s2 += __shfl_xor(s2, 32, 64);
    if (quad == 0) so[sb + w*32 + nt*16 + l16] = s2;
  }
  __syncthreads();                      // B2: vs dead; region A reusable

  // out-stage in own-wave slice of region A; writes land in the block's
  // contiguous [64][128] plane (64B runs per d-row per wave)
  __bf16* oS = (__bf16*)(smem + 4608*w);   // [64][36] bf16
  #pragma unroll
  for (int m0 = 0; m0 < 4; ++m0)
    #pragma unroll
    for (int nt = 0; nt < 2; ++nt) {
      bf4 ov;
      #pragma unroll
      for (int rg = 0; rg < 4; ++rg) ov[rg] = (__bf16)acc[m0][nt][rg];
      *(bf4*)&oS[(m0*16 + l16)*36 + nt*16 + quad*4] = ov;
    }
  ushort* dp = (ushort*)dst + plane + w*32;
  ushort* oSu = (ushort*)oS;
  #pragma unroll
  for (int it = 0; it < 4; ++it) {
    int i = it*64 + lane;
    int d = i >> 2, ch = i & 3;
    uint2 lo  = *(const uint2*)&oSu[d*36 + ch*8];
    uint2 hi2 = *(const uint2*)&oSu[d*36 + ch*8 + 4];
    uint4 uu; uu.x = lo.x; uu.y = lo.y; uu.z = hi2.x; uu.w = hi2.y;
    *(uint4*)&dp[(size_t)d*128 + ch*8] = uu;
  }
}

// Fused scale+combine:  Bo = gamma*(Bo + oT^T)/(sW+sH) + A  (R-form), with
// oT in T-form; optionally writes Bo^T into BoT (T-form; may alias oT).
// 16x16 threads, 2-wide x (ushort2/float2 traffic).
__global__ __launch_bounds__(256) void combineT_kernel(
    __bf16* __restrict__ Bo, const __bf16* oT,
    const __bf16* __restrict__ A,
    const float* __restrict__ sW, const float* __restrict__ sH,
    const float* __restrict__ gamma, __bf16* BoT, int writeT) {
  __shared__ float tile[32][33], ts[32][33];
  __shared__ float rt[32][33];
  int tx = threadIdx.x, ty = threadIdx.y;       // 16x16
  int n = blockIdx.z;                           // b*64 + d
  int b = n >> 6, d = n & 63;
  int x0 = blockIdx.x*32, y0 = blockIdx.y*32;   // x0 = h-tile, y0 = w-tile
  const ushort* ip = (const ushort*)oT;
  const float* shp = sH + b*16384;
  for (int i = ty; i < 32; i += 16) {
    // T(b, y0+i, d, x0+2tx)
    ushort2 u = *(const ushort2*)
        &ip[(((size_t)b*128 + y0 + i)*64 + d)*128 + x0 + 2*tx];
    tile[i][2*tx]     = (float)*(__bf16*)&u.x;
    tile[i][2*tx + 1] = (float)*(__bf16*)&u.y;
    float2 s2 = *(const float2*)&shp[(y0 + i)*128 + x0 + 2*tx];
    ts[i][2*tx] = s2.x; ts[i][2*tx + 1] = s2.y;
  }
  __syncthreads();
  float g = *gamma;
  for (int i2 = ty; i2 < 32; i2 += 16) {
    int h = x0 + i2, w2 = y0 + 2*tx;
    size_t idx = (((size_t)b*128 + h)*64 + d)*128 + w2;   // R(b,h,d,w2)
    int pix = b*16384 + h*128 + w2;
    float2 swv = *(const float2*)&sW[pix];
    ushort2 bo = *(const ushort2*)((const ushort*)Bo + idx);
    ushort2 aa = *(const ushort2*)((const ushort*)A + idx);
    float inv0 = 1.0f/(swv.x + ts[2*tx][i2]);
    float r0 = g*((float)*(__bf16*)&bo.x + tile[2*tx][i2])*inv0
               + (float)*(__bf16*)&aa.x;
    float inv1 = 1.0f/(swv.y + ts[2*tx + 1][i2]);
    float r1 = g*((float)*(__bf16*)&bo.y + tile[2*tx + 1][i2])*inv1
               + (float)*(__bf16*)&aa.y;
    ushort2 o; o.x = bfb(r0); o.y = bfb(r1);
    *(ushort2*)((ushort*)Bo + idx) = o;
    rt[i2][2*tx] = r0; rt[i2][2*tx + 1] = r1;
  }
  if (writeT) {
    __syncthreads();
    for (int i = ty; i < 32; i += 16) {
      ushort2 o;
      o.x = bfb(rt[2*tx][i]); o.y = bfb(rt[2*tx + 1][i]);
      // T(b, y0+i, d, x0+2tx)
      *(ushort2*)((ushort*)BoT +
                  (((size_t)b*128 + y0 + i)*64 + d)*128 + x0 + 2*tx) = o;
    }
  }
}

// MFMA pointwise 64->64 per (b,r) slice: out[o][p] = sum_c wpw[o][c]*A[c][p].
// A in R-form -> contiguous 16KB read/block.  out layout fixed [b][o][h][w].
// Staged coalesced loads; ONE barrier; SWAPPED MFMA -> p-major f32 acc
// stored direct (16B segments, 64 o at 64KB stride).  LDS 18432.
__global__ __launch_bounds__(256) void pw_kernel(
    const __bf16* __restrict__ A, const __bf16* __restrict__ ptab,
    float* __restrict__ out) {
  __shared__ __align__(16) char smem[18432];
  __bf16* ys = (__bf16*)smem;
  int t = threadIdx.x;
  int r = blockIdx.x, b = blockIdx.y;
  const ushort* sp = (const ushort*)A + ((size_t)b*128 + r)*8192;
  {
    int a = t & 15, cp = t >> 4;
    ushort* yr = (ushort*)ys;
    #pragma unroll
    for (int q = 0; q < 2; ++q) {
      int c = 2*cp + 32*q;
      uint4 u0 = *(const uint4*)&sp[(size_t)c*128 + a*8];
      uint4 u1 = *(const uint4*)&sp[(size_t)(c + 1)*128 + a*8];
      const ushort* p0 = (const ushort*)&u0;
      const ushort* p1 = (const ushort*)&u1;
      int cx = (((c >> 3) ^ a) & 7)*8 + (c & 7);
      #pragma unroll
      for (int j = 0; j < 8; ++j) {
        ushort2 uv; uv.x = p0[j]; uv.y = p1[j];
        *(ushort2*)&yr[(a*8 + j)*72 + cx] = uv;
      }
    }
  }
  int lane = t & 63, w = t >> 6;
  int l16 = lane & 15, quad = lane >> 4;
  __syncthreads();                     // ys staged
  bf8 b_ys[2][2];
  #pragma unroll
  for (int nt = 0; nt < 2; ++nt) {
    int p = w*32 + nt*16 + l16;
    int hi = (p >> 3) & 7;
    #pragma unroll
    for (int s = 0; s < 2; ++s)
      b_ys[nt][s] = *(const bf8*)&ys[p*72 + ((s*4 + quad) ^ hi)*8];
  }
  f4 z4 = {0.f, 0.f, 0.f, 0.f};
  float* dp = out + (size_t)b*1048576 + (size_t)r*128;
  #pragma unroll
  for (int m0 = 0; m0 < 4; ++m0) {
    bf8 aw0 = *(const bf8*)&ptab[((m0*2 + 0)*64 + lane)*8];
    bf8 aw1 = *(const bf8*)&ptab[((m0*2 + 1)*64 + lane)*8];
    #pragma unroll
    for (int nt = 0; nt < 2; ++nt) {
      f4 a2 = z4;
      a2 = MFMA(b_ys[nt][0], aw0, a2);
      a2 = MFMA(b_ys[nt][1], aw1, a2);
      *(f4*)&dp[(size_t)(m0*16 + l16)*16384 + w*32 + nt*16 + quad*4] = a2;
    }
  }
}

extern "C" void kernel_launch(void* const* d_in, const int* in_sizes, int n_in,
                              void* d_out, int out_size, void* d_ws, size_t ws_size,
                              hipStream_t stream) {
  const float* x     = (const float*)d_in[0];
  const float* wdw   = (const float*)d_in[1];
  const float* wq    = (const float*)d_in[2];
  const float* wk    = (const float*)d_in[3];
  const float* wv    = (const float*)d_in[4];
  const float* gamma = (const float*)d_in[5];
  const float* wpw   = (const float*)d_in[6];
  float* out = (float*)d_out;

  // Workspace: y,z,AT bf16 (16 MB each) + wtab/ptab + 2 fp32 stat planes.
  __bf16* y    = (__bf16*)d_ws;
  __bf16* z    = y + 8388608;
  __bf16* AT   = z + 8388608;
  __bf16* wtab = AT + 8388608;        // 10 frags x 64 lanes x 8 = 5120
  __bf16* ptab = wtab + 5120;         // 8 frags x 64 lanes x 8 = 4096
  float* sW = (float*)(ptab + 4096);
  float* sH = sW + 131072;
  size_t need = (size_t)3*8388608*2 + (5120 + 4096)*2 + (size_t)2*131072*4;
  if (ws_size < need) return;

  dwconv_kernel<<<dim3(4, 4, 512), 256, 0, stream>>>(
      x, wdw, y, AT, wq, wk, wv, wpw, wtab, ptab);

  for (int pass = 0; pass < 2; ++pass) {
    const __bf16* A = pass ? z : y;   // CCA input / residual (R-form)
    __bf16* Bo      = pass ? y : z;   // CCA output (R-form)

    ccdir_kernel<<<dim3(128, 8, 2), 256, 0, stream>>>(
        A, Bo, AT, wtab, sW, sH);
    // pass 0: also write Bo^T into AT (next pass's transposed input)
    combineT_kernel<<<dim3(4, 4, 512), dim3(16, 16), 0, stream>>>(
        Bo, AT, A, sW, sH, gamma, AT, pass == 0 ? 1 : 0);
  }

  pw_kernel<<<dim3(128, 8), 256, 0, stream>>>(y, ptab, out);
}